// Round 1
// baseline (1384.036 us; speedup 1.0000x reference)
//
#include <hip/hip_runtime.h>

// StaticImagePrimalDualNN: Chambolle-Pock primal-dual iteration, T=128 steps.
// B=4, H=W=512, fp32, periodic boundaries (jnp.roll semantics).
//
// Per-step fused kernel. Intra-step "new q at (i-1,j)/(i,j-1)" dependency is
// handled by redundant recompute (same formula, same inputs -> identical
// rounding). xbar and q ping-pong in d_ws; p updates in place; x0 lives in
// d_out (in-place update), so d_out holds x1 after the last step.

#define B_ 4
#define H_ 512
#define W_ 512

__device__ __forceinline__ float clampl(float v, float l) {
    return fminf(fmaxf(v, -l), l);
}

__global__ __launch_bounds__(256) void pdnn_init(
    const float* __restrict__ x, float* __restrict__ xbar,
    float* __restrict__ p, float* __restrict__ qx, float* __restrict__ qy,
    float* __restrict__ x0, int n4)
{
    int t = blockIdx.x * blockDim.x + threadIdx.x;
    if (t >= n4) return;
    float4 v = ((const float4*)x)[t];
    ((float4*)xbar)[t] = v;
    ((float4*)p)[t]    = v;   // carry init: p0 = x
    ((float4*)x0)[t]   = v;   // x0 = x (lives in d_out)
    float4 z = make_float4(0.f, 0.f, 0.f, 0.f);
    ((float4*)qx)[t] = z;
    ((float4*)qy)[t] = z;
}

__global__ __launch_bounds__(256) void pdnn_step(
    const float* __restrict__ xn, const float* __restrict__ lam,
    const float* __restrict__ xbar_in, float* __restrict__ xbar_out,
    const float* __restrict__ qx_in,  float* __restrict__ qx_out,
    const float* __restrict__ qy_in,  float* __restrict__ qy_out,
    float* __restrict__ p, float* __restrict__ x0,
    const float* __restrict__ tau_p, const float* __restrict__ sigma_p,
    const float* __restrict__ theta_p)
{
    const int W4 = W_ / 4;
    int t = blockIdx.x * blockDim.x + threadIdx.x;
    if (t >= B_ * H_ * W4) return;
    int c = t % W4;
    int r = t / W4;
    int i = r % H_;
    int b = r / H_;

    const float Linv = 0.27735009811261457f; // 1/sqrt(13)
    float sg = Linv / (1.f + __expf(-sigma_p[0]));  // sigmoid(sigma)/L
    float ta = Linv / (1.f + __expf(-tau_p[0]));    // sigmoid(tau)/L
    float th = 1.f  / (1.f + __expf(-theta_p[0]));  // sigmoid(theta)
    float inv1ps = 1.f / (1.f + sg);

    const size_t plane = (size_t)H_ * W_;
    int j0  = c * 4;
    int im1 = i ? i - 1 : H_ - 1;
    int ip1 = (i == H_ - 1) ? 0 : i + 1;
    int jm1 = j0 ? j0 - 1 : W_ - 1;
    int jp4 = (j0 + 4 == W_) ? 0 : j0 + 4;

    size_t rowb   = (size_t)b * plane + (size_t)i * W_;
    size_t base   = rowb + j0;
    size_t base_u = (size_t)b * plane + (size_t)im1 * W_ + j0;
    size_t base_d = (size_t)b * plane + (size_t)ip1 * W_ + j0;
    size_t lrow0  = (size_t)b * 2 * plane + (size_t)i * W_;
    size_t lb0    = lrow0 + j0;
    size_t lb0u   = (size_t)b * 2 * plane + (size_t)im1 * W_ + j0;
    size_t lrow1  = (size_t)b * 2 * plane + plane + (size_t)i * W_;
    size_t lb1    = lrow1 + j0;

    // ---- loads (all float4 except 4 wrap scalars) ----
    float4 xb4  = *(const float4*)(xbar_in + base);
    float4 xbu4 = *(const float4*)(xbar_in + base_u);
    float4 xbd4 = *(const float4*)(xbar_in + base_d);
    float  xbl  = xbar_in[rowb + jm1];
    float  xbr  = xbar_in[rowb + jp4];
    float4 qx4  = *(const float4*)(qx_in + base);
    float4 qxu4 = *(const float4*)(qx_in + base_u);
    float4 qy4  = *(const float4*)(qy_in + base);
    float  qyl  = qy_in[rowb + jm1];
    float4 l04  = *(const float4*)(lam + lb0);
    float4 l0u4 = *(const float4*)(lam + lb0u);
    float4 l14  = *(const float4*)(lam + lb1);
    float  l1l  = lam[lrow1 + jm1];
    float4 p4   = *(const float4*)(p + base);
    float4 x04  = *(const float4*)(x0 + base);
    float4 xn4  = *(const float4*)(xn + base);

    float xb[6]  = {xbl, xb4.x, xb4.y, xb4.z, xb4.w, xbr};
    float xbu[4] = {xbu4.x, xbu4.y, xbu4.z, xbu4.w};
    float xbd[4] = {xbd4.x, xbd4.y, xbd4.z, xbd4.w};
    float qxc[4] = {qx4.x, qx4.y, qx4.z, qx4.w};
    float qxu[4] = {qxu4.x, qxu4.y, qxu4.z, qxu4.w};
    float qyc[4] = {qy4.x, qy4.y, qy4.z, qy4.w};
    float l0c[4] = {l04.x, l04.y, l04.z, l04.w};
    float l0u[4] = {l0u4.x, l0u4.y, l0u4.z, l0u4.w};
    float l1c[4] = {l14.x, l14.y, l14.z, l14.w};
    float pa[4]  = {p4.x, p4.y, p4.z, p4.w};
    float x0a[4] = {x04.x, x04.y, x04.z, x04.w};
    float xna[4] = {xn4.x, xn4.y, xn4.z, xn4.w};

    // new qy at columns j0-1 .. j0+3 (qyn[0] is the redundant left recompute)
    float qyn[5];
    qyn[0] = clampl(qyl + sg * (xb[1] - xb[0]), l1l);
    #pragma unroll
    for (int k = 0; k < 4; ++k)
        qyn[k + 1] = clampl(qyc[k] + sg * (xb[k + 2] - xb[k + 1]), l1c[k]);

    float qxn[4], qxnu[4], pn[4], x1[4], xbn[4];
    #pragma unroll
    for (int k = 0; k < 4; ++k) {
        qxn[k]  = clampl(qxc[k] + sg * (xbd[k] - xb[k + 1]), l0c[k]);       // new qx(i,j)
        qxnu[k] = clampl(qxu[k] + sg * (xb[k + 1] - xbu[k]), l0u[k]);       // new qx(i-1,j), redundant
        pn[k]   = (pa[k] + sg * (xb[k + 1] - xna[k])) * inv1ps;
        float dv = (qxnu[k] - qxn[k]) + (qyn[k] - qyn[k + 1]);              // -div(q_new)... (grad_GH)
        x1[k]   = x0a[k] - ta * pn[k] - ta * dv;
        xbn[k]  = x1[k] + th * (x1[k] - x0a[k]);
    }

    *(float4*)(xbar_out + base) = make_float4(xbn[0], xbn[1], xbn[2], xbn[3]);
    *(float4*)(qx_out + base)   = make_float4(qxn[0], qxn[1], qxn[2], qxn[3]);
    *(float4*)(qy_out + base)   = make_float4(qyn[1], qyn[2], qyn[3], qyn[4]);
    *(float4*)(p + base)        = make_float4(pn[0], pn[1], pn[2], pn[3]);
    *(float4*)(x0 + base)       = make_float4(x1[0], x1[1], x1[2], x1[3]);
}

extern "C" void kernel_launch(void* const* d_in, const int* in_sizes, int n_in,
                              void* d_out, int out_size, void* d_ws, size_t ws_size,
                              hipStream_t stream) {
    const float* x       = (const float*)d_in[0];
    const float* lam     = (const float*)d_in[1];
    const float* tau_p   = (const float*)d_in[2];
    const float* sigma_p = (const float*)d_in[3];
    const float* theta_p = (const float*)d_in[4];
    // d_in[5] = T (device int). Cannot be read host-side under graph capture;
    // setup_inputs() fixes T=128.
    const int T = 128;

    float* out = (float*)d_out;
    float* ws  = (float*)d_ws;
    const size_t N = (size_t)B_ * H_ * W_;   // 1,048,576
    float* xbarA = ws + 0 * N;
    float* xbarB = ws + 1 * N;
    float* qxA   = ws + 2 * N;
    float* qxB   = ws + 3 * N;
    float* qyA   = ws + 4 * N;
    float* qyB   = ws + 5 * N;
    float* p     = ws + 6 * N;               // 28 MB total scratch

    int n4 = (int)(N / 4);
    dim3 blk(256);
    dim3 grd((n4 + 255) / 256);              // 1024 blocks

    pdnn_init<<<grd, blk, 0, stream>>>(x, xbarA, p, qxA, qyA, out, n4);

    for (int t = 0; t < T; ++t) {
        const float *xi, *qxi, *qyi;
        float *xo, *qxo, *qyo;
        if (t & 1) { xi = xbarB; xo = xbarA; qxi = qxB; qxo = qxA; qyi = qyB; qyo = qyA; }
        else       { xi = xbarA; xo = xbarB; qxi = qxA; qxo = qxB; qyi = qyA; qyo = qyB; }
        pdnn_step<<<grd, blk, 0, stream>>>(x, lam, xi, xo, qxi, qxo, qyi, qyo,
                                           p, out, tau_p, sigma_p, theta_p);
    }
}